// Round 4
// baseline (541.004 us; speedup 1.0000x reference)
//
#include <hip/hip_runtime.h>
#include <hip/hip_bf16.h>
#include <stdint.h>

#define NN 8192   // nodes (= in_feats)
#define DD 512    // feature dim
#define EE 262144 // edges

typedef __attribute__((ext_vector_type(8))) short short8;
typedef __attribute__((ext_vector_type(4))) float f32x4;

__device__ __forceinline__ unsigned short f2bf_rne(float f) {
    unsigned u = __float_as_uint(f);
    u += 0x7fffu + ((u >> 16) & 1u);
    return (unsigned short)(u >> 16);
}

__device__ __forceinline__ void gload_lds16(const void* g, void* l) {
    __builtin_amdgcn_global_load_lds(
        (const __attribute__((address_space(1))) unsigned int*)g,
        (__attribute__((address_space(3))) unsigned int*)l, 16, 0, 0);
}

// ---- zero deg + cursor (8192 each) ----
__global__ void k_init(int* deg, int* cursor) {
    int i = blockIdx.x * 256 + threadIdx.x;
    if (i < NN) { deg[i] = 0; cursor[i] = 0; }
}

// ---- degree histogram ----
__global__ void k_hist(const int* __restrict__ row, int* __restrict__ deg) {
    int e = blockIdx.x * 256 + threadIdx.x;
    if (e < EE) atomicAdd(&deg[row[e]], 1);
}

// ---- exclusive scan over 8192 degrees (1 block, 256 thr, 32/thread) ----
__global__ void k_scan(const int* __restrict__ deg, int* __restrict__ offsets,
                       int* __restrict__ cursor) {
    __shared__ int psum[256];
    int t = threadIdx.x;
    int base = t * 32;
    int local[32];
    int s = 0;
    for (int i = 0; i < 32; i++) { local[i] = s; s += deg[base + i]; }
    psum[t] = s;
    __syncthreads();
    int pre = 0;
    for (int i = 0; i < t; i++) pre += psum[i];  // tiny kernel, O(256) serial ok
    for (int i = 0; i < 32; i++) {
        int v = pre + local[i];
        offsets[base + i] = v;
        cursor[base + i] = v;
    }
    if (t == 255) offsets[NN] = pre + s;
}

// ---- scatter edges into CSR ----
__global__ void k_scatter(const int* __restrict__ row, const int* __restrict__ col,
                          int* __restrict__ cursor, int* __restrict__ csr) {
    int e = blockIdx.x * 256 + threadIdx.x;
    if (e < EE) {
        int r = row[e];
        int p = atomicAdd(&cursor[r], 1);
        csr[p] = col[e];
    }
}

// ---- transpose x [512][8192] f32 -> xTb [8192][512] bf16 ----
__global__ void k_xt(const float* __restrict__ x, unsigned short* __restrict__ xTb) {
    __shared__ float tile[32][33];
    int tx = threadIdx.x & 31, ty = threadIdx.x >> 5;  // 256 thr: ty 0..7
    int n0 = blockIdx.x * 32;   // along N (256 blocks)
    int d0 = blockIdx.y * 32;   // along D (16 blocks)
    #pragma unroll
    for (int i = 0; i < 32; i += 8)
        tile[ty + i][tx] = x[(size_t)(d0 + ty + i) * NN + n0 + tx];
    __syncthreads();
    #pragma unroll
    for (int i = 0; i < 32; i += 8)
        xTb[(size_t)(n0 + ty + i) * DD + d0 + tx] = f2bf_rne(tile[tx][ty + i]);
}

// ---- aggregate: block per node; gather neighbor rows of xTb, mean, write hTb [N][D] bf16 ----
__global__ void k_agg(const unsigned short* __restrict__ xTb, const int* __restrict__ offsets,
                      const int* __restrict__ csr, unsigned short* __restrict__ hTb) {
    __shared__ int nb[128];
    int r = blockIdx.x;
    int t = threadIdx.x;  // 128 threads, thread t owns features 4t..4t+3
    int s = offsets[r], e = offsets[r + 1];
    int d = e - s;
    float inv = 1.0f / (float)(d > 0 ? d : 1);
    float a0 = 0.f, a1 = 0.f, a2 = 0.f, a3 = 0.f;
    for (int base = s; base < e; base += 128) {
        int cnt = min(128, e - base);
        if (t < cnt) nb[t] = csr[base + t];
        __syncthreads();
        for (int j = 0; j < cnt; j++) {
            int c = nb[j];
            uint2 u = *(const uint2*)(xTb + (size_t)c * DD + t * 4);
            a0 += __uint_as_float(u.x << 16);
            a1 += __uint_as_float(u.x & 0xffff0000u);
            a2 += __uint_as_float(u.y << 16);
            a3 += __uint_as_float(u.y & 0xffff0000u);
        }
        __syncthreads();
    }
    unsigned short o0 = f2bf_rne(a0 * inv), o1 = f2bf_rne(a1 * inv);
    unsigned short o2 = f2bf_rne(a2 * inv), o3 = f2bf_rne(a3 * inv);
    ushort4 o = make_ushort4(o0, o1, o2, o3);
    *(ushort4*)(hTb + (size_t)r * DD + t * 4) = o;
}

// ---- transpose hTb [8192][512] bf16 -> hA [512][8192] bf16 (GEMM A layout) ----
__global__ void k_ht(const unsigned short* __restrict__ hTb, unsigned short* __restrict__ hA) {
    __shared__ unsigned short tile[32][33];
    int tx = threadIdx.x & 31, ty = threadIdx.x >> 5;
    int r0 = blockIdx.x * 32;   // along N
    int d0 = blockIdx.y * 32;   // along D
    #pragma unroll
    for (int i = 0; i < 32; i += 8)
        tile[ty + i][tx] = hTb[(size_t)(r0 + ty + i) * DD + d0 + tx];
    __syncthreads();
    #pragma unroll
    for (int i = 0; i < 32; i += 8)
        hA[(size_t)(d0 + ty + i) * NN + r0 + tx] = tile[tx][ty + i];
}

// ---- zero the fp32 partial buffer (16MB = all of d_out) ----
__global__ void k_zero(float4* part) {
    int i = blockIdx.x * 256 + threadIdx.x;  // 1M float4
    part[i] = make_float4(0.f, 0.f, 0.f, 0.f);
}

// ==== GEMM: part[m][n] += sum_k hA[m][k] * W[n][k]; BM=256, BN=128, BK=64, splitK=2 ====
// Round-4: BM 128 -> 256. Evidence: r0/r1/r3 (three different schedules: 2-barrier,
// splitK=4, dbuf issue-early) ALL land at exactly 175us with identical counters ->
// schedule-invariant => BANDWIDTH WALL, not latency. Cache-level traffic was
// (512/BM)x256MB W + (8192/BN)x8MB A = 1.0+0.5 GB; 1.5GB/175us = 8.6 TB/s at the
// L2/L3 level (HBM only 1.05 TB/s; L3 retains W) -- the fabric/L3 ceiling.
// BM=256 halves W traffic -> 1.03 GB total. 512 thr (8 waves, 4m x 2n), same
// 64x64/wave tile + 64-reg acc. LDS 100KB -> 1 block/CU = 8 waves/CU (occupancy
// unchanged vs 2x256-thr blocks). Grid 256 = 1/CU exactly.
// Keep r3 single-barrier dbuf body (neutral r0->r3; safer at 1 block/CU).
// A-tile XOR-chunk swizzle unchanged (global_load_lds forbids padded dst).
__global__ __launch_bounds__(512, 2)
void k_gemm(const unsigned short* __restrict__ hA, const float* __restrict__ W,
            float* __restrict__ part) {
    __shared__ unsigned short As[2][256 * 64];  // 2 x 32KB, chunk-swizzled k
    __shared__ unsigned short Bs[2][128 * 72];  // 2 x 18KB, padded stride 144B

    // bid -> (mt, nt, ks): the 2 mt-partners of a (nt,ks) share the same 128-row
    // W panel; keep them on one XCD (dispatch round-robins bid%8).
    const int bid = blockIdx.x;            // 0..255
    const int x = bid & 7;                 // XCD
    const int l = bid >> 3;                // 0..31
    const int mt = l & 1;
    const int g = (l >> 1) * 8 + x;        // 0..127 = (nt,ks)
    const int nt = g >> 1;                 // 0..63
    const int ks = g & 1;
    const int m0 = mt * 256, n0 = nt * 128;
    const int kbeg = ks * 4096, kend = kbeg + 4096;

    const int tid = threadIdx.x;           // 0..511
    const int lane = tid & 63, wave = tid >> 6;      // wave 0..7
    const int wm = (wave & 3) * 64, wn = (wave >> 2) * 64;
    const int l15 = lane & 15, quad = lane >> 4;

    f32x4 acc[4][4];
    #pragma unroll
    for (int i = 0; i < 4; i++)
        #pragma unroll
        for (int j = 0; j < 4; j++) acc[i][j] = (f32x4){0.f, 0.f, 0.f, 0.f};

    const int arow = tid >> 3;                         // 0..63
    const int acol_log = ((tid & 7) ^ (arow & 7)) * 8; // swizzled source chunk (bf16 idx)
    const int aphys = (tid & 7) * 8;                   // LDS dst chunk = tid*16B (uniform)
    const int brow = tid >> 4;                         // 0..31 (+i*32)
    const int bc4 = tid & 15;                          // float4 index in row

    float4 wv[4];

    // ---- prologue: stage tile kbeg into buffer 0 ----
    #pragma unroll
    for (int i = 0; i < 4; i++)
        wv[i] = *(const float4*)(W + (size_t)(n0 + brow + i * 32) * NN + kbeg + bc4 * 4);
    #pragma unroll
    for (int i = 0; i < 4; i++) {
        int r = arow + i * 64;  // r&7 == arow&7, swizzle consistent
        gload_lds16(hA + (size_t)(m0 + r) * NN + kbeg + acol_log, &As[0][r * 64 + aphys]);
    }
    #pragma unroll
    for (int i = 0; i < 4; i++) {
        unsigned p0 = __builtin_amdgcn_perm(__float_as_uint(wv[i].y) + 0x8000u,
                                            __float_as_uint(wv[i].x) + 0x8000u, 0x07060302u);
        unsigned p1 = __builtin_amdgcn_perm(__float_as_uint(wv[i].w) + 0x8000u,
                                            __float_as_uint(wv[i].z) + 0x8000u, 0x07060302u);
        *(uint2*)&Bs[0][(brow + i * 32) * 72 + bc4 * 4] = make_uint2(p0, p1);
    }
    __syncthreads();

    int cur = 0;
    for (int k0 = kbeg; k0 < kend; k0 += 64) {
        const bool has_next = (k0 + 64 < kend);  // wave-uniform
        if (has_next) {
            // issue next tile's loads early; W first (pack waits only these)
            #pragma unroll
            for (int i = 0; i < 4; i++)
                wv[i] = *(const float4*)(W + (size_t)(n0 + brow + i * 32) * NN +
                                         (k0 + 64) + bc4 * 4);
            #pragma unroll
            for (int i = 0; i < 4; i++) {
                int r = arow + i * 64;
                gload_lds16(hA + (size_t)(m0 + r) * NN + (k0 + 64) + acol_log,
                            &As[cur ^ 1][r * 64 + aphys]);
            }
            // pin the issue point: hipcc otherwise sinks loads to their uses (r2)
            __builtin_amdgcn_sched_barrier(0);
        }
        // ---- compute current tile from buf[cur] ----
        #pragma unroll
        for (int kk = 0; kk < 64; kk += 32) {
            short8 af[4], bf[4];
            #pragma unroll
            for (int mi = 0; mi < 4; mi++) {
                int row = wm + mi * 16 + l15;   // 0..255
                int pc = (((kk >> 3) + quad) ^ (l15 & 7)) * 8;  // un-swizzle
                af[mi] = *(const short8*)&As[cur][row * 64 + pc];
            }
            #pragma unroll
            for (int ni = 0; ni < 4; ni++)
                bf[ni] = *(const short8*)&Bs[cur][(wn + ni * 16 + l15) * 72 + kk + quad * 8];
            #pragma unroll
            for (int mi = 0; mi < 4; mi++)
                #pragma unroll
                for (int ni = 0; ni < 4; ni++)
                    acc[mi][ni] = __builtin_amdgcn_mfma_f32_16x16x32_bf16(
                        af[mi], bf[ni], acc[mi][ni], 0, 0, 0);
        }
        // ---- late write: pack W(t+1) into Bs[cur^1] ----
        if (has_next) {
            #pragma unroll
            for (int i = 0; i < 4; i++) {
                unsigned p0 = __builtin_amdgcn_perm(__float_as_uint(wv[i].y) + 0x8000u,
                                                    __float_as_uint(wv[i].x) + 0x8000u, 0x07060302u);
                unsigned p1 = __builtin_amdgcn_perm(__float_as_uint(wv[i].w) + 0x8000u,
                                                    __float_as_uint(wv[i].z) + 0x8000u, 0x07060302u);
                *(uint2*)&Bs[cur ^ 1][(brow + i * 32) * 72 + bc4 * 4] = make_uint2(p0, p1);
            }
        }
        __syncthreads();  // drains aged A-glds + ds_writes
        cur ^= 1;
    }

    // epilogue: C/D layout col=lane&15 (n), row=quad*4+i (m)  [m89-verified]
    #pragma unroll
    for (int mi = 0; mi < 4; mi++)
        #pragma unroll
        for (int ni = 0; ni < 4; ni++) {
            int mrow = m0 + wm + mi * 16 + quad * 4;
            int ncol = n0 + wn + ni * 16 + l15;
            #pragma unroll
            for (int i = 0; i < 4; i++)
                atomicAdd(&part[(size_t)(mrow + i) * NN + ncol], acc[mi][ni][i]);
        }
}

// ---- relu in place on d_out ----
__global__ void k_relu(float4* __restrict__ buf) {
    int i = blockIdx.x * 256 + threadIdx.x;  // 1M float4
    float4 v = buf[i];
    buf[i] = make_float4(fmaxf(v.x, 0.f), fmaxf(v.y, 0.f), fmaxf(v.z, 0.f), fmaxf(v.w, 0.f));
}

extern "C" void kernel_launch(void* const* d_in, const int* in_sizes, int n_in,
                              void* d_out, int out_size, void* d_ws, size_t ws_size,
                              hipStream_t stream) {
    const float* x = (const float*)d_in[0];     // [512][8192]
    const int* adj = (const int*)d_in[1];       // [2][262144]
    const float* W = (const float*)d_in[2];     // [8192][8192]
    char* ws = (char*)d_ws;

    const int* row = adj;
    const int* col = adj + EE;

    // ws peak ~10.2 MB; d_out (16 MB fp32) recycled:
    //   phase A: hTb (bf16 [N][D], 8 MB) in d_out[0..8MB)
    //   phase B: part (fp32 [D][N], 16 MB) IS d_out (k_zero reclaims it)
    int* deg = (int*)(ws + 0);                              //  32 KB
    int* cursor = (int*)(ws + 32768);                       //  32 KB
    int* offsets = (int*)(ws + 65536);                      //  32 KB + 4
    int* csr = (int*)(ws + 131072);                         //   1 MB  [128KB,1.125MB)
    unsigned short* xTb = (unsigned short*)(ws + (2u << 20)); // 8 MB [2MB,10MB)
    unsigned short* hA = xTb;                               // alias: xTb dead after k_agg
    unsigned short* hTb = (unsigned short*)d_out;           // 8 MB in d_out
    float* part = (float*)d_out;                            // 16 MB (hTb dead by then)

    k_init<<<32, 256, 0, stream>>>(deg, cursor);
    k_hist<<<EE / 256, 256, 0, stream>>>(row, deg);
    k_scan<<<1, 256, 0, stream>>>(deg, offsets, cursor);
    k_scatter<<<EE / 256, 256, 0, stream>>>(row, col, cursor, csr);
    k_xt<<<dim3(NN / 32, DD / 32), 256, 0, stream>>>(x, xTb);
    k_agg<<<NN, 128, 0, stream>>>(xTb, offsets, csr, hTb);
    k_ht<<<dim3(NN / 32, DD / 32), 256, 0, stream>>>(hTb, hA);   // reads d_out, writes ws
    k_zero<<<4096, 256, 0, stream>>>((float4*)part);             // reclaims d_out
    k_gemm<<<256, 512, 0, stream>>>(hA, W, part);
    k_relu<<<4096, 256, 0, stream>>>((float4*)part);             // in-place
}

// Round 5
// 519.534 us; speedup vs baseline: 1.0413x; 1.0413x over previous
//
#include <hip/hip_runtime.h>
#include <hip/hip_bf16.h>
#include <stdint.h>

#define NN 8192   // nodes (= in_feats)
#define DD 512    // feature dim
#define EE 262144 // edges

typedef __attribute__((ext_vector_type(8))) short short8;
typedef __attribute__((ext_vector_type(4))) float f32x4;

__device__ __forceinline__ unsigned short f2bf_rne(float f) {
    unsigned u = __float_as_uint(f);
    u += 0x7fffu + ((u >> 16) & 1u);
    return (unsigned short)(u >> 16);
}

__device__ __forceinline__ void gload_lds16(const void* g, void* l) {
    __builtin_amdgcn_global_load_lds(
        (const __attribute__((address_space(1))) unsigned int*)g,
        (__attribute__((address_space(3))) unsigned int*)l, 16, 0, 0);
}

// ---- zero deg + cursor (8192 each) ----
__global__ void k_init(int* deg, int* cursor) {
    int i = blockIdx.x * 256 + threadIdx.x;
    if (i < NN) { deg[i] = 0; cursor[i] = 0; }
}

// ---- degree histogram ----
__global__ void k_hist(const int* __restrict__ row, int* __restrict__ deg) {
    int e = blockIdx.x * 256 + threadIdx.x;
    if (e < EE) atomicAdd(&deg[row[e]], 1);
}

// ---- exclusive scan over 8192 degrees (1 block, 256 thr, 32/thread) ----
__global__ void k_scan(const int* __restrict__ deg, int* __restrict__ offsets,
                       int* __restrict__ cursor) {
    __shared__ int psum[256];
    int t = threadIdx.x;
    int base = t * 32;
    int local[32];
    int s = 0;
    for (int i = 0; i < 32; i++) { local[i] = s; s += deg[base + i]; }
    psum[t] = s;
    __syncthreads();
    int pre = 0;
    for (int i = 0; i < t; i++) pre += psum[i];  // tiny kernel, O(256) serial ok
    for (int i = 0; i < 32; i++) {
        int v = pre + local[i];
        offsets[base + i] = v;
        cursor[base + i] = v;
    }
    if (t == 255) offsets[NN] = pre + s;
}

// ---- scatter edges into CSR ----
__global__ void k_scatter(const int* __restrict__ row, const int* __restrict__ col,
                          int* __restrict__ cursor, int* __restrict__ csr) {
    int e = blockIdx.x * 256 + threadIdx.x;
    if (e < EE) {
        int r = row[e];
        int p = atomicAdd(&cursor[r], 1);
        csr[p] = col[e];
    }
}

// ---- transpose x [512][8192] f32 -> xTb [8192][512] bf16 ----
__global__ void k_xt(const float* __restrict__ x, unsigned short* __restrict__ xTb) {
    __shared__ float tile[32][33];
    int tx = threadIdx.x & 31, ty = threadIdx.x >> 5;  // 256 thr: ty 0..7
    int n0 = blockIdx.x * 32;   // along N (256 blocks)
    int d0 = blockIdx.y * 32;   // along D (16 blocks)
    #pragma unroll
    for (int i = 0; i < 32; i += 8)
        tile[ty + i][tx] = x[(size_t)(d0 + ty + i) * NN + n0 + tx];
    __syncthreads();
    #pragma unroll
    for (int i = 0; i < 32; i += 8)
        xTb[(size_t)(n0 + ty + i) * DD + d0 + tx] = f2bf_rne(tile[tx][ty + i]);
}

// ---- aggregate: block per node; gather neighbor rows of xTb, mean, write hTb [N][D] bf16 ----
__global__ void k_agg(const unsigned short* __restrict__ xTb, const int* __restrict__ offsets,
                      const int* __restrict__ csr, unsigned short* __restrict__ hTb) {
    __shared__ int nb[128];
    int r = blockIdx.x;
    int t = threadIdx.x;  // 128 threads, thread t owns features 4t..4t+3
    int s = offsets[r], e = offsets[r + 1];
    int d = e - s;
    float inv = 1.0f / (float)(d > 0 ? d : 1);
    float a0 = 0.f, a1 = 0.f, a2 = 0.f, a3 = 0.f;
    for (int base = s; base < e; base += 128) {
        int cnt = min(128, e - base);
        if (t < cnt) nb[t] = csr[base + t];
        __syncthreads();
        for (int j = 0; j < cnt; j++) {
            int c = nb[j];
            uint2 u = *(const uint2*)(xTb + (size_t)c * DD + t * 4);
            a0 += __uint_as_float(u.x << 16);
            a1 += __uint_as_float(u.x & 0xffff0000u);
            a2 += __uint_as_float(u.y << 16);
            a3 += __uint_as_float(u.y & 0xffff0000u);
        }
        __syncthreads();
    }
    unsigned short o0 = f2bf_rne(a0 * inv), o1 = f2bf_rne(a1 * inv);
    unsigned short o2 = f2bf_rne(a2 * inv), o3 = f2bf_rne(a3 * inv);
    ushort4 o = make_ushort4(o0, o1, o2, o3);
    *(ushort4*)(hTb + (size_t)r * DD + t * 4) = o;
}

// ---- transpose hTb [8192][512] bf16 -> hA [512][8192] bf16 (GEMM A layout) ----
__global__ void k_ht(const unsigned short* __restrict__ hTb, unsigned short* __restrict__ hA) {
    __shared__ unsigned short tile[32][33];
    int tx = threadIdx.x & 31, ty = threadIdx.x >> 5;
    int r0 = blockIdx.x * 32;   // along N
    int d0 = blockIdx.y * 32;   // along D
    #pragma unroll
    for (int i = 0; i < 32; i += 8)
        tile[ty + i][tx] = hTb[(size_t)(r0 + ty + i) * DD + d0 + tx];
    __syncthreads();
    #pragma unroll
    for (int i = 0; i < 32; i += 8)
        hA[(size_t)(d0 + ty + i) * NN + r0 + tx] = tile[tx][ty + i];
}

// ---- zero the fp32 partial buffer (16MB = all of d_out) ----
__global__ void k_zero(float4* part) {
    int i = blockIdx.x * 256 + threadIdx.x;  // 1M float4
    part[i] = make_float4(0.f, 0.f, 0.f, 0.f);
}

// ==== GEMM: part[m][n] += sum_k hA[m][k] * W[n][k]; BM=BN=128, BK=128, splitK=2 ====
// Round-5: BK 64 -> 128 on the proven r0 2-barrier body. Evidence so far:
//   r0 (2-barrier, BK64)=175us; r1 (splitK4)=175; r3 (dbuf issue-early)=175;
//   r4 (BM256, halved traffic)=185. Schedule-invariant AND traffic-invariant.
// The one invariant: sequential barrier-steps per CU = 64 in ALL variants
// (r0/r3: 2 blk x 64 conc.; r1: 2 rounds x 32; r4: 1 blk x 64), at a constant
// ~6560 cy/step -- a barrier-lockstep convoy (phases serialize through LDS port
// -> MFMA -> TA/vmem -> pack with no cross-phase overlap), not a BW wall
// (MfmaUtil 15%, VALU 13%, HBM 13%: nothing saturated).
// BK=128 halves the step count (32 steps): if the convoy cost is per-step,
// dur -> ~105-125us. If dur is unchanged, per-step cost scales with per-step
// staging volume -> next lever is halving W bytes (bf16 pre-cast).
// LDS: As 32KB + Bs 128x136x2B = 34.8KB -> 67.6KB, still 2 blocks/CU.
// Swizzle algebra unchanged: phys chunk = log ^ (row&7) (low-3-bit XOR of 16
// chunks/row keeps 8 distinct bank-quads per 16-lane group = 2-way = free).
// launch_bounds (256,2): (256,4) caps VGPR at 64 -> scratch spills (history).
__global__ __launch_bounds__(256, 2)
void k_gemm(const unsigned short* __restrict__ hA, const float* __restrict__ W,
            float* __restrict__ part) {
    __shared__ unsigned short As[128 * 128];  // 32KB, chunk-swizzled k (16 chunks/row)
    __shared__ unsigned short Bs[128 * 136];  // 34.8KB, padded stride 272B (2-way = free)

    const int bid = blockIdx.x;                    // 0..511
    const int g = (bid & 7) | ((bid >> 5) << 3);   // 0..127: mt-partners share XCD
    const int mt = (bid >> 3) & 3;
    const int nt = g >> 1;
    const int ks = g & 1;
    const int m0 = mt * 128, n0 = nt * 128;
    const int kbeg = ks * 4096, kend = kbeg + 4096;

    const int tid = threadIdx.x;
    const int lane = tid & 63, wave = tid >> 6;
    const int wm = (wave & 1) * 64, wn = (wave >> 1) * 64;
    const int l15 = lane & 15, quad = lane >> 4;

    f32x4 acc[4][4];
    #pragma unroll
    for (int i = 0; i < 4; i++)
        #pragma unroll
        for (int j = 0; j < 4; j++) acc[i][j] = (f32x4){0.f, 0.f, 0.f, 0.f};

    const int arow = tid >> 4;                          // 0..15 (+i*16)
    const int achunk = tid & 15;                        // phys chunk (LDS dst, linear)
    const int acol_log = (achunk ^ (arow & 7)) * 8;     // (arow+i*16)&7 == arow&7
    const int aphys = achunk * 8;

    for (int k0 = kbeg; k0 < kend; k0 += 128) {
        __syncthreads();  // protect LDS from previous iteration's readers
        // A tile: 128(m) x 128(k) bf16 via async global->LDS, 8x 16B/lane, swizzled
        #pragma unroll
        for (int i = 0; i < 8; i++) {
            int r = arow + i * 16;
            gload_lds16(hA + (size_t)(m0 + r) * NN + k0 + acol_log, &As[r * 128 + aphys]);
        }
        // B tile: 128(n) x 128(k) fp32 -> bf16, two batches of 8 float4/thread
        {
            float4 wv[8];
            #pragma unroll
            for (int i = 0; i < 8; i++) {
                int fid = tid + i * 256;       // 0..2047: rows 0..63
                int rw = fid >> 5, c4 = fid & 31;
                wv[i] = *(const float4*)(W + (size_t)(n0 + rw) * NN + k0 + c4 * 4);
            }
            #pragma unroll
            for (int i = 0; i < 8; i++) {
                int fid = tid + i * 256;
                int rw = fid >> 5, c4 = fid & 31;
                unsigned p0 = __builtin_amdgcn_perm(__float_as_uint(wv[i].y) + 0x8000u,
                                                    __float_as_uint(wv[i].x) + 0x8000u, 0x07060302u);
                unsigned p1 = __builtin_amdgcn_perm(__float_as_uint(wv[i].w) + 0x8000u,
                                                    __float_as_uint(wv[i].z) + 0x8000u, 0x07060302u);
                *(uint2*)&Bs[rw * 136 + c4 * 4] = make_uint2(p0, p1);
            }
            #pragma unroll
            for (int i = 0; i < 8; i++) {
                int fid = tid + (i + 8) * 256; // 2048..4095: rows 64..127
                int rw = fid >> 5, c4 = fid & 31;
                wv[i] = *(const float4*)(W + (size_t)(n0 + rw) * NN + k0 + c4 * 4);
            }
            #pragma unroll
            for (int i = 0; i < 8; i++) {
                int fid = tid + (i + 8) * 256;
                int rw = fid >> 5, c4 = fid & 31;
                unsigned p0 = __builtin_amdgcn_perm(__float_as_uint(wv[i].y) + 0x8000u,
                                                    __float_as_uint(wv[i].x) + 0x8000u, 0x07060302u);
                unsigned p1 = __builtin_amdgcn_perm(__float_as_uint(wv[i].w) + 0x8000u,
                                                    __float_as_uint(wv[i].z) + 0x8000u, 0x07060302u);
                *(uint2*)&Bs[rw * 136 + c4 * 4] = make_uint2(p0, p1);
            }
        }
        __syncthreads();  // drains vmcnt (global_load_lds) + lgkmcnt (ds_write)
        #pragma unroll
        for (int kk = 0; kk < 128; kk += 32) {
            short8 af[4], bf[4];
            #pragma unroll
            for (int mi = 0; mi < 4; mi++) {
                int row = wm + mi * 16 + l15;
                int pc = (((kk >> 3) + quad) ^ (l15 & 7)) * 8;  // un-swizzle
                af[mi] = *(const short8*)&As[row * 128 + pc];
            }
            #pragma unroll
            for (int ni = 0; ni < 4; ni++)
                bf[ni] = *(const short8*)&Bs[(wn + ni * 16 + l15) * 136 + kk + quad * 8];
            #pragma unroll
            for (int mi = 0; mi < 4; mi++)
                #pragma unroll
                for (int ni = 0; ni < 4; ni++)
                    acc[mi][ni] = __builtin_amdgcn_mfma_f32_16x16x32_bf16(
                        af[mi], bf[ni], acc[mi][ni], 0, 0, 0);
        }
    }
    // epilogue: C/D layout col=lane&15 (n), row=quad*4+i (m)  [m89-verified]
    #pragma unroll
    for (int mi = 0; mi < 4; mi++)
        #pragma unroll
        for (int ni = 0; ni < 4; ni++) {
            int mrow = m0 + wm + mi * 16 + quad * 4;
            int ncol = n0 + wn + ni * 16 + l15;
            #pragma unroll
            for (int i = 0; i < 4; i++)
                atomicAdd(&part[(size_t)(mrow + i) * NN + ncol], acc[mi][ni][i]);
        }
}

// ---- relu in place on d_out ----
__global__ void k_relu(float4* __restrict__ buf) {
    int i = blockIdx.x * 256 + threadIdx.x;  // 1M float4
    float4 v = buf[i];
    buf[i] = make_float4(fmaxf(v.x, 0.f), fmaxf(v.y, 0.f), fmaxf(v.z, 0.f), fmaxf(v.w, 0.f));
}

extern "C" void kernel_launch(void* const* d_in, const int* in_sizes, int n_in,
                              void* d_out, int out_size, void* d_ws, size_t ws_size,
                              hipStream_t stream) {
    const float* x = (const float*)d_in[0];     // [512][8192]
    const int* adj = (const int*)d_in[1];       // [2][262144]
    const float* W = (const float*)d_in[2];     // [8192][8192]
    char* ws = (char*)d_ws;

    const int* row = adj;
    const int* col = adj + EE;

    // ws peak ~10.2 MB; d_out (16 MB fp32) recycled:
    //   phase A: hTb (bf16 [N][D], 8 MB) in d_out[0..8MB)
    //   phase B: part (fp32 [D][N], 16 MB) IS d_out (k_zero reclaims it)
    int* deg = (int*)(ws + 0);                              //  32 KB
    int* cursor = (int*)(ws + 32768);                       //  32 KB
    int* offsets = (int*)(ws + 65536);                      //  32 KB + 4
    int* csr = (int*)(ws + 131072);                         //   1 MB  [128KB,1.125MB)
    unsigned short* xTb = (unsigned short*)(ws + (2u << 20)); // 8 MB [2MB,10MB)
    unsigned short* hA = xTb;                               // alias: xTb dead after k_agg
    unsigned short* hTb = (unsigned short*)d_out;           // 8 MB in d_out
    float* part = (float*)d_out;                            // 16 MB (hTb dead by then)

    k_init<<<32, 256, 0, stream>>>(deg, cursor);
    k_hist<<<EE / 256, 256, 0, stream>>>(row, deg);
    k_scan<<<1, 256, 0, stream>>>(deg, offsets, cursor);
    k_scatter<<<EE / 256, 256, 0, stream>>>(row, col, cursor, csr);
    k_xt<<<dim3(NN / 32, DD / 32), 256, 0, stream>>>(x, xTb);
    k_agg<<<NN, 128, 0, stream>>>(xTb, offsets, csr, hTb);
    k_ht<<<dim3(NN / 32, DD / 32), 256, 0, stream>>>(hTb, hA);   // reads d_out, writes ws
    k_zero<<<4096, 256, 0, stream>>>((float4*)part);             // reclaims d_out
    k_gemm<<<512, 256, 0, stream>>>(hA, W, part);
    k_relu<<<4096, 256, 0, stream>>>((float4*)part);             // in-place
}